// Round 8
// baseline (431.427 us; speedup 1.0000x reference)
//
#include <hip/hip_runtime.h>

typedef unsigned long long u64;
typedef unsigned int u32;
typedef unsigned short u16;

#define MSORT 4096     // sort capacity (power of 2); K ~2000 for this input
#define TPB   256
#define BOXCAP 3648    // 57*64 boxes staged in LDS (57 KB)
#define RSLOT_W 10     // register slots per wave (covers K <= 2560 all-register)
#define KPC   300      // kept per class (only top-300/class can reach global top-300)
#define SELCAP 1024
#define RPT  (MSORT / TPB)

#define WG_SCOPE __HIP_MEMORY_SCOPE_WORKGROUP

// LDS layout (bytes):
//  [0,     58368)  float4 boxes[3648]  (aliased: u64 sortbuf[4096] = 32 KB during sort)
//  [58368, 58976)  u16 keptR[304]
//  [58976, 58988)  u32 ctl[3] = {cntK, activeW, doneF}
//  [58992, 63856)  float4 pubBox[304]
//  [63856, 63860)  int cntS

__device__ __forceinline__ float boxArea(float4 b) {
    return __fmul_rn(__fsub_rn(b.z, b.x), __fsub_rn(b.w, b.y));
}

// exact numpy f32 semantics: RN32(inter/uni) > T  <=>  inter (cmp) B*uni in f64
template<bool GE>
__device__ __forceinline__ bool iou_gt(float4 a, float area_a, float4 b, float area_b, double B) {
    float ix1 = fmaxf(a.x, b.x), iy1 = fmaxf(a.y, b.y);
    float ix2 = fminf(a.z, b.z), iy2 = fminf(a.w, b.w);
    float iw  = fmaxf(__fsub_rn(ix2, ix1), 0.0f);
    float ih  = fmaxf(__fsub_rn(iy2, iy1), 0.0f);
    float inter = __fmul_rn(iw, ih);
    float uni   = __fsub_rn(__fadd_rn(area_a, area_b), inter);
    return GE ? ((double)inter >= B * (double)uni) : ((double)inter > B * (double)uni);
}

// eager sweep of this wave's own register slots (+ LDS tail if K > 2560)
template<bool GE>
__device__ __forceinline__ u64 sweep_own(
    float4 bi, float area_i, const float4 (&breg)[RSLOT_W],
    const float (&areaj)[RSLOT_W], const float4* __restrict__ boxesLds,
    int base, int nslots, int lane, double B)
{
    u64 ns = 0;
    #pragma unroll
    for (int t = 0; t < RSLOT_W; t++)
        ns |= ((u64)iou_gt<GE>(bi, area_i, breg[t], areaj[t], B)) << (base + t);
    for (int t = RSLOT_W; t < nslots; t++) {
        float4 bj = boxesLds[((base + t) << 6) | lane];
        ns |= ((u64)iou_gt<GE>(bi, area_i, bj, boxArea(bj), B)) << (base + t);
    }
    return ns;
}

// Barrier-free producer/consumer greedy NMS with LAZY active sweep.
// Wave w owns contiguous slots [base,end). Passive waves eagerly apply each
// published kept box to their whole range. The active wave applies a new kept
// box to the CURRENT slot only (1 IoU on the critical path); when the cursor
// enters a new slot it "prepares" it: loads that slot's box column into
// registers and applies the backlog kept[seen0..nk) (pipelined broadcast
// reads, off the per-step path).
template<bool GE>
__device__ __forceinline__ void greedy_nms(
    const float4* __restrict__ boxesLds, u16* __restrict__ keptR,
    float4* __restrict__ pubBox, u32* __restrict__ ctl,
    int K, int smax, double B, int lane, int wave)
{
    const int SW   = (smax + 3) >> 2;
    const int base = (wave * SW < smax) ? wave * SW : smax;
    const int end  = (base + SW < smax) ? base + SW : smax;
    const int nslots = end - base;

    float4 breg[RSLOT_W];
    float  areaj[RSLOT_W];
    #pragma unroll
    for (int t = 0; t < RSLOT_W; t++) {
        float4 b = boxesLds[((base + t) << 6) | lane];
        breg[t] = b;
        areaj[t] = boxArea(b);
    }

    u64 sup;
    {
        int t = (lane < K) ? ((K - lane + 63) >> 6) : 0;  // valid slots for this lane
        sup = (t >= 64) ? 0ull : (~0ull << t);
    }

    u32 seen = 0;
    if (wave != 0) {
        // ---- passive phase: consume published boxes until our turn (or done)
        for (;;) {
            u32 d  = __hip_atomic_load(&ctl[2], __ATOMIC_ACQUIRE, WG_SCOPE);
            u32 cn = __hip_atomic_load(&ctl[0], __ATOMIC_ACQUIRE, WG_SCOPE);
            bool prog = (seen < cn);
            while (seen < cn) {
                float4 bi = pubBox[seen]; seen++;
                sup |= sweep_own<GE>(bi, boxArea(bi), breg, areaj, boxesLds, base, nslots, lane, B);
            }
            if (d) return;
            u32 aw = __hip_atomic_load(&ctl[1], __ATOMIC_ACQUIRE, WG_SCOPE);
            if (aw == (u32)wave) {
                u32 cn2 = __hip_atomic_load(&ctl[0], __ATOMIC_ACQUIRE, WG_SCOPE);
                while (seen < cn2) {                       // final drain (cn2 is final)
                    float4 bi = pubBox[seen]; seen++;
                    sup |= sweep_own<GE>(bi, boxArea(bi), breg, areaj, boxesLds, base, nslots, lane, B);
                }
                break;                                     // become active
            }
            if (!prog) __builtin_amdgcn_s_sleep(1);
        }
    }

    // ---- active phase (lazy)
    u32 nk = seen;
    const u32 seen0 = seen;   // kept[0..seen0) already applied to ALL own slots
    int scur = base - 1;      // last prepared slot
    float4 bcur = make_float4(0.f, 0.f, 0.f, 0.f);
    float  acur = 0.f;
    int js = base << 6;

    for (;;) {
        int s = js >> 6;
        while (s > scur) {                                 // prepare newly entered slots
            scur++;
            if (scur < end) {
                bcur = boxesLds[(scur << 6) | lane];
                acur = boxArea(bcur);
                u64 bit = 0;
                for (u32 k = seen0; k < nk; k++) {         // backlog: uniform broadcast reads
                    float4 bk = pubBox[k];
                    bit |= ((u64)iou_gt<GE>(bk, boxArea(bk), bcur, acur, B));
                }
                sup |= bit << scur;
            }
        }
        if (scur >= end) {                                 // range exhausted: hand off
            if (lane == 0) {
                if (wave == 3) __hip_atomic_store(&ctl[2], 1u, __ATOMIC_RELEASE, WG_SCOPE);
                else           __hip_atomic_store(&ctl[1], (u32)(wave + 1), __ATOMIC_RELEASE, WG_SCOPE);
            }
            return;
        }
        u64 bal = __ballot((int)(((~sup) >> scur) & 1ull)) & (~0ull << (js & 63));
        if (bal == 0) { js = (scur + 1) << 6; continue; }
        int i = (scur << 6) + (int)__builtin_ctzll(bal);

        float4 bi = boxesLds[i];                           // uniform broadcast read
        if (lane == 0) { pubBox[nk] = bi; keptR[nk] = (u16)i; }
        nk++;
        if (nk >= KPC) {                                   // global top-300 can't need more
            if (lane == 0) {
                __hip_atomic_store(&ctl[0], nk, __ATOMIC_RELEASE, WG_SCOPE);
                __hip_atomic_store(&ctl[2], 1u, __ATOMIC_RELEASE, WG_SCOPE);
            }
            return;
        }
        if (lane == 0) __hip_atomic_store(&ctl[0], nk, __ATOMIC_RELEASE, WG_SCOPE);
        // lazy: apply kept box to CURRENT slot only (1 IoU on critical path)
        sup |= ((u64)iou_gt<GE>(bi, boxArea(bi), bcur, acur, B)) << scur;
        js = i + 1;
    }
}

// ---------------------------------------------------------------------------
// Per-class kernel.
// ---------------------------------------------------------------------------
__global__ __launch_bounds__(TPB, 1) void nms_class_kernel(
    const float* __restrict__ bboxes, const float* __restrict__ scores,
    const float* __restrict__ conf_ptr, const float* __restrict__ nms_ptr,
    int N, int C, u32* __restrict__ gidx, u64* __restrict__ gkept)
{
    __shared__ __align__(16) char smem[63860];
    u64*    sortbuf  = (u64*)smem;
    float4* boxesLds = (float4*)smem;
    u16*    keptR    = (u16*)(smem + 58368);
    u32*    ctl      = (u32*)(smem + 58976);
    float4* pubBox   = (float4*)(smem + 58992);
    int*    cntS     = (int*)(smem + 63856);

    const int tid = threadIdx.x;
    const int c   = blockIdx.x;               // fg class 0..nc-1
    const int cls = c + 1;
    const float conf = *conf_ptr;
    const float nmsT = *nms_ptr;

    // ---- phase 1: compact valid candidates. key = score_bits<<32 | idx
    // (desc sort of key == argsort(masked)[::-1] incl. tie order: larger idx first)
    if (tid == 0) *cntS = 0;
    __syncthreads();
    for (int i = tid; i < N; i += TPB) {
        float s = scores[(size_t)i * C + cls];
        if (s > conf) {
            int p = atomicAdd(cntS, 1);
            if (p < MSORT) sortbuf[p] = ((u64)__float_as_uint(s) << 32) | (u32)i;
        }
    }
    __syncthreads();
    int K = *cntS; if (K > BOXCAP) K = BOXCAP;
    for (int p = K + tid; p < MSORT; p += TPB) sortbuf[p] = 0;
    __syncthreads();

    // ---- phase 2: bitonic sort descending
    for (int kk = 2; kk <= MSORT; kk <<= 1) {
        for (int j = kk >> 1; j > 0; j >>= 1) {
            for (int i = tid; i < MSORT; i += TPB) {
                int ixj = i ^ j;
                if (ixj > i) {
                    u64 a = sortbuf[i], b = sortbuf[ixj];
                    if (((i & kk) == 0) ? (a < b) : (a > b)) { sortbuf[i] = b; sortbuf[ixj] = a; }
                }
            }
            __syncthreads();
        }
    }

    // ---- phase 3: keys -> registers; barrier; write gidx + gather boxes into
    // LDS (clobbers sortbuf). Garbage rows beyond K: suppression bits pre-set,
    // never read.
    u32 myIdx[RPT];
    #pragma unroll
    for (int t = 0; t < RPT; t++) myIdx[t] = (u32)sortbuf[t * TPB + tid];
    __syncthreads();
    u32* gidx_c = gidx + (size_t)c * MSORT;
    #pragma unroll
    for (int t = 0; t < RPT; t++) {
        int r = t * TPB + tid;
        if (r < K) {
            u32 idx = myIdx[t];
            gidx_c[r] = idx;
            boxesLds[r] = ((const float4*)bboxes)[idx];
        }
    }
    if (tid == 0) { ctl[0] = 0; ctl[1] = 0; ctl[2] = 0; }
    __syncthreads();

    const int lane = tid & 63;
    const int wave = tid >> 6;

    // B = midpoint(T, nextafter(T)); cmp is >= iff nextafter(T) has even mantissa.
    const u32 tb = __float_as_uint(nmsT);
    const float Tn = __uint_as_float(tb + 1u);
    const double B = ((double)nmsT + (double)Tn) * 0.5;
    const bool geCmp = (((tb + 1u) & 1u) == 0u);

    const int smax = (K + 63) >> 6;            // <= 57
    if (geCmp) greedy_nms<true >(boxesLds, keptR, pubBox, ctl, K, smax, B, lane, wave);
    else       greedy_nms<false>(boxesLds, keptR, pubBox, ctl, K, smax, B, lane, wave);
    __syncthreads();                           // all waves done; keptR/cntK visible

    // ---- epilogue: build kept keys in parallel (all 256 threads)
    int kept = (int)ctl[0]; if (kept > KPC) kept = KPC;
    u64* gkept_c = gkept + (size_t)c * KPC;
    for (int p = tid; p < kept; p += TPB) {
        int rank = keptR[p];
        u32 idx  = gidx_c[rank];
        float sc = scores[(size_t)idx * C + cls];
        u32 flat = (u32)c * (u32)N + idx;      // top_k ties: lower flat first
        gkept_c[p] = ((u64)__float_as_uint(sc) << 32) | (u32)(~flat);
    }
    for (int p = kept + tid; p < KPC; p += TPB) gkept_c[p] = 0;
}

// ---------------------------------------------------------------------------
// Global top-Mout over nc*KPC kept keys: 2048-bin histogram select + 1024-slot
// LDS bitonic sort.
// ---------------------------------------------------------------------------
__global__ __launch_bounds__(1024) void nms_topk_kernel(
    const float* __restrict__ bboxes, const u64* __restrict__ gkept,
    int N, int nc, int Mout, float* __restrict__ out)
{
    __shared__ u32 hist[2048];
    __shared__ int chunk[64];
    __shared__ int selCount;
    __shared__ int bstarS;
    __shared__ u64 sel[SELCAP];

    const int tid = threadIdx.x;
    const int total = nc * KPC;

    for (int b = tid; b < 2048; b += 1024) hist[b] = 0;
    if (tid == 0) selCount = 0;
    __syncthreads();

    for (int t = tid; t < total; t += 1024) {
        u64 k = gkept[t];
        if (k) {
            int b = (int)((u32)(k >> 44)) - 0x3F000;
            b = b < 0 ? 0 : (b > 2047 ? 2047 : b);
            atomicAdd(&hist[b], 1u);
        }
    }
    __syncthreads();

    if (tid < 64) {
        int s = 0;
        #pragma unroll
        for (int b = 0; b < 32; b++) s += (int)hist[tid * 32 + b];
        chunk[tid] = s;
    }
    __syncthreads();

    if (tid == 0) {
        int acc = 0, ch = 63;
        for (; ch >= 0; ch--) {
            if (acc + chunk[ch] >= Mout) break;
            acc += chunk[ch];
        }
        int bs = 0;
        if (ch >= 0) {
            int b = (ch << 5) + 31;
            for (; b >= (ch << 5); b--) { acc += (int)hist[b]; if (acc >= Mout) break; }
            bs = (b < (ch << 5)) ? (ch << 5) : b;
        }
        bstarS = bs;
    }
    __syncthreads();
    const int bstar = bstarS;

    for (int t = tid; t < total; t += 1024) {
        u64 k = gkept[t];
        if (k) {
            int b = (int)((u32)(k >> 44)) - 0x3F000;
            b = b < 0 ? 0 : (b > 2047 ? 2047 : b);
            if (b >= bstar) {
                int p = atomicAdd(&selCount, 1);
                if (p < SELCAP) sel[p] = k;
            }
        }
    }
    __syncthreads();
    int cnt = selCount; if (cnt > SELCAP) cnt = SELCAP;
    for (int p = cnt + tid; p < SELCAP; p += 1024) sel[p] = 0;
    __syncthreads();

    for (int kk = 2; kk <= SELCAP; kk <<= 1) {
        for (int j = kk >> 1; j > 0; j >>= 1) {
            int i = tid;
            int ixj = i ^ j;
            if (i < SELCAP && ixj > i) {
                u64 a = sel[i], b = sel[ixj];
                if (((i & kk) == 0) ? (a < b) : (a > b)) { sel[i] = b; sel[ixj] = a; }
            }
            __syncthreads();
        }
    }

    for (int t = tid; t < Mout; t += 1024) {
        u64 k = (t < SELCAP) ? sel[t] : 0;
        float px1 = 0.f, py1 = 0.f, px2 = 0.f, py2 = 0.f, ps = 0.f, plab = -1.0f;
        if (k) {
            float s  = __uint_as_float((u32)(k >> 32));
            u32 flat = ~((u32)k);
            int cc   = (int)(flat / (u32)N);
            int box  = (int)(flat - (u32)cc * (u32)N);
            float4 bb = ((const float4*)bboxes)[box];
            px1 = bb.x; py1 = bb.y; px2 = bb.z; py2 = bb.w; ps = s;
            plab = (float)(cc + 1);
        }
        out[t * 5 + 0] = px1;
        out[t * 5 + 1] = py1;
        out[t * 5 + 2] = px2;
        out[t * 5 + 3] = py2;
        out[t * 5 + 4] = ps;
        out[Mout * 5 + t] = plab;
    }
}

extern "C" void kernel_launch(void* const* d_in, const int* in_sizes, int n_in,
                              void* d_out, int out_size, void* d_ws, size_t ws_size,
                              hipStream_t stream) {
    const float* bboxes = (const float*)d_in[0];
    const float* scores = (const float*)d_in[1];
    const float* conf   = (const float*)d_in[2];
    const float* nmsT   = (const float*)d_in[3];

    const int N    = in_sizes[0] / 4;        // 5000
    const int C    = in_sizes[1] / N;        // 81
    const int nc   = C - 1;                  // 80
    const int Mout = out_size / 6;           // 300

    // ws layout: [gidx: nc*MSORT u32 = 1.31 MB][gkept: nc*KPC u64 = 192 KB]
    u32* gidx  = (u32*)d_ws;
    u64* gkept = (u64*)((char*)d_ws + (size_t)nc * MSORT * sizeof(u32));

    nms_class_kernel<<<nc, TPB, 0, stream>>>(bboxes, scores, conf, nmsT, N, C, gidx, gkept);
    nms_topk_kernel<<<1, 1024, 0, stream>>>(bboxes, gkept, N, nc, Mout, (float*)d_out);
}

// Round 9
// 336.610 us; speedup vs baseline: 1.2817x; 1.2817x over previous
//
#include <hip/hip_runtime.h>

typedef unsigned long long u64;
typedef unsigned int u32;
typedef unsigned short u16;

#define MSORT 4096     // max sort capacity (power of 2)
#define TPB_S 1024     // sort kernel threads
#define TPB   256      // greedy kernel threads
#define BOXCAP 3648    // 57*64 boxes staged in LDS (57 KB)
#define RSLOT_W 10     // register slots per wave (covers K <= 2560 all-register)
#define KPC   300      // kept per class (only top-300/class can reach global top-300)
#define SELCAP 1024

#define WG_SCOPE __HIP_MEMORY_SCOPE_WORKGROUP

__device__ __forceinline__ float boxArea(float4 b) {
    return __fmul_rn(__fsub_rn(b.z, b.x), __fsub_rn(b.w, b.y));
}

// exact numpy f32 semantics: RN32(inter/uni) > T  <=>  inter (cmp) B*uni in f64
template<bool GE>
__device__ __forceinline__ bool iou_gt(float4 a, float area_a, float4 b, float area_b, double B) {
    float ix1 = fmaxf(a.x, b.x), iy1 = fmaxf(a.y, b.y);
    float ix2 = fminf(a.z, b.z), iy2 = fminf(a.w, b.w);
    float iw  = fmaxf(__fsub_rn(ix2, ix1), 0.0f);
    float ih  = fmaxf(__fsub_rn(iy2, iy1), 0.0f);
    float inter = __fmul_rn(iw, ih);
    float uni   = __fsub_rn(__fadd_rn(area_a, area_b), inter);
    return GE ? ((double)inter >= B * (double)uni) : ((double)inter > B * (double)uni);
}

// ---------------------------------------------------------------------------
// Kernel 1: per-class compact + runtime-sized bitonic sort (desc).
// key = score_bits<<32 | idx  ==  argsort(masked)[::-1] incl. tie order.
// 1024 threads: 4x the parallelism of the old fused front-end; M = next
// pow2 >= K (~2048) instead of fixed 4096.
// ---------------------------------------------------------------------------
__global__ __launch_bounds__(TPB_S, 1) void nms_sort_kernel(
    const float* __restrict__ scores, const float* __restrict__ conf_ptr,
    int N, int C, u32* __restrict__ gidx, u32* __restrict__ gK)
{
    __shared__ u64 sortbuf[MSORT];
    __shared__ int cntS;

    const int tid = threadIdx.x;
    const int c   = blockIdx.x;
    const int cls = c + 1;
    const float conf = *conf_ptr;

    if (tid == 0) cntS = 0;
    __syncthreads();
    for (int i = tid; i < N; i += TPB_S) {
        float s = scores[(size_t)i * C + cls];
        if (s > conf) {
            int p = atomicAdd(&cntS, 1);
            if (p < MSORT) sortbuf[p] = ((u64)__float_as_uint(s) << 32) | (u32)i;
        }
    }
    __syncthreads();
    int K = cntS; if (K > BOXCAP) K = BOXCAP;
    int M = 64; while (M < K) M <<= 1;          // runtime sort size
    for (int p = K + tid; p < M; p += TPB_S) sortbuf[p] = 0;
    __syncthreads();

    for (int kk = 2; kk <= M; kk <<= 1) {
        for (int j = kk >> 1; j > 0; j >>= 1) {
            for (int i = tid; i < M; i += TPB_S) {
                int ixj = i ^ j;
                if (ixj > i) {
                    u64 a = sortbuf[i], b = sortbuf[ixj];
                    if (((i & kk) == 0) ? (a < b) : (a > b)) { sortbuf[i] = b; sortbuf[ixj] = a; }
                }
            }
            __syncthreads();
        }
    }

    u32* gidx_c = gidx + (size_t)c * MSORT;
    for (int r = tid; r < K; r += TPB_S) gidx_c[r] = (u32)sortbuf[r];
    if (tid == 0) gK[c] = (u32)K;
}

// eager sweep of this wave's own register slots (+ LDS tail if nslots > 10)
template<bool GE>
__device__ __forceinline__ u64 sweep_own(
    float4 bi, float area_i, const float4 (&breg)[RSLOT_W],
    const float (&areaj)[RSLOT_W], const float4* __restrict__ boxesLds,
    int base, int nslots, int lane, double B)
{
    u64 ns = 0;
    #pragma unroll
    for (int t = 0; t < RSLOT_W; t++)
        ns |= ((u64)iou_gt<GE>(bi, area_i, breg[t], areaj[t], B)) << (base + t);
    for (int t = RSLOT_W; t < nslots; t++) {
        float4 bj = boxesLds[((base + t) << 6) | lane];
        ns |= ((u64)iou_gt<GE>(bi, area_i, bj, boxArea(bj), B)) << (base + t);
    }
    return ns;
}

// Barrier-free producer/consumer greedy NMS with lazy active sweep (R8).
// Returns total kept count if THIS wave set doneF (it then owns the
// epilogue), else -1.
template<bool GE>
__device__ __forceinline__ int greedy_nms(
    const float4* __restrict__ boxesLds, u16* __restrict__ keptR,
    float4* __restrict__ pubBox, u32* __restrict__ ctl,
    int K, int smax, double B, int lane, int wave)
{
    const int SW   = (smax + 3) >> 2;
    const int base = (wave * SW < smax) ? wave * SW : smax;
    const int end  = (base + SW < smax) ? base + SW : smax;
    const int nslots = end - base;

    float4 breg[RSLOT_W];
    float  areaj[RSLOT_W];
    #pragma unroll
    for (int t = 0; t < RSLOT_W; t++) {
        float4 b = boxesLds[((base + t) << 6) | lane];
        breg[t] = b;
        areaj[t] = boxArea(b);
    }

    u64 sup;
    {
        int t = (lane < K) ? ((K - lane + 63) >> 6) : 0;  // valid slots for this lane
        sup = (t >= 64) ? 0ull : (~0ull << t);
    }

    u32 seen = 0;
    if (wave != 0) {
        // ---- passive phase: consume published boxes until our turn (or done)
        for (;;) {
            u32 d  = __hip_atomic_load(&ctl[2], __ATOMIC_ACQUIRE, WG_SCOPE);
            u32 cn = __hip_atomic_load(&ctl[0], __ATOMIC_ACQUIRE, WG_SCOPE);
            bool prog = (seen < cn);
            while (seen < cn) {
                float4 bi = pubBox[seen]; seen++;
                sup |= sweep_own<GE>(bi, boxArea(bi), breg, areaj, boxesLds, base, nslots, lane, B);
            }
            if (d) return -1;
            u32 aw = __hip_atomic_load(&ctl[1], __ATOMIC_ACQUIRE, WG_SCOPE);
            if (aw == (u32)wave) {
                u32 cn2 = __hip_atomic_load(&ctl[0], __ATOMIC_ACQUIRE, WG_SCOPE);
                while (seen < cn2) {                       // final drain (cn2 is final)
                    float4 bi = pubBox[seen]; seen++;
                    sup |= sweep_own<GE>(bi, boxArea(bi), breg, areaj, boxesLds, base, nslots, lane, B);
                }
                break;                                     // become active
            }
            if (!prog) __builtin_amdgcn_s_sleep(1);
        }
    }

    // ---- active phase (lazy)
    u32 nk = seen;
    const u32 seen0 = seen;   // kept[0..seen0) already applied to ALL own slots
    int scur = base - 1;      // last prepared slot
    float4 bcur = make_float4(0.f, 0.f, 0.f, 0.f);
    float  acur = 0.f;
    int js = base << 6;

    for (;;) {
        int s = js >> 6;
        while (s > scur) {                                 // prepare newly entered slots
            scur++;
            if (scur < end) {
                bcur = boxesLds[(scur << 6) | lane];
                acur = boxArea(bcur);
                u64 bit = 0;
                for (u32 k = seen0; k < nk; k++) {         // backlog: uniform broadcast reads
                    float4 bk = pubBox[k];
                    bit |= ((u64)iou_gt<GE>(bk, boxArea(bk), bcur, acur, B));
                }
                sup |= bit << scur;
            }
        }
        if (scur >= end) {                                 // range exhausted
            if (wave == 3) {
                if (lane == 0) __hip_atomic_store(&ctl[2], 1u, __ATOMIC_RELEASE, WG_SCOPE);
                return (int)nk;                            // last wave: total kept final
            }
            if (lane == 0) __hip_atomic_store(&ctl[1], (u32)(wave + 1), __ATOMIC_RELEASE, WG_SCOPE);
            return -1;
        }
        u64 bal = __ballot((int)(((~sup) >> scur) & 1ull)) & (~0ull << (js & 63));
        if (bal == 0) { js = (scur + 1) << 6; continue; }
        int i = (scur << 6) + (int)__builtin_ctzll(bal);

        float4 bi = boxesLds[i];                           // uniform broadcast read
        if (lane == 0) { pubBox[nk] = bi; keptR[nk] = (u16)i; }
        nk++;
        if (nk >= KPC) {                                   // global top-300 can't need more
            if (lane == 0) {
                __hip_atomic_store(&ctl[0], nk, __ATOMIC_RELEASE, WG_SCOPE);
                __hip_atomic_store(&ctl[2], 1u, __ATOMIC_RELEASE, WG_SCOPE);
            }
            return (int)nk;
        }
        if (lane == 0) __hip_atomic_store(&ctl[0], nk, __ATOMIC_RELEASE, WG_SCOPE);
        // lazy: apply kept box to CURRENT slot only (1 IoU on critical path)
        sup |= ((u64)iou_gt<GE>(bi, boxArea(bi), bcur, acur, B)) << scur;
        js = i + 1;
    }
}

// ---------------------------------------------------------------------------
// Kernel 2: per-class greedy NMS. Stages boxes from gidx, runs the lazy
// producer/consumer greedy; the doneF-setting wave writes the kept keys.
// LDS: [0,58368) float4 boxes[3648]; [58368,58976) u16 keptR[304];
//      [58976,58988) u32 ctl[3]; [58992,63856) float4 pubBox[304]
// ---------------------------------------------------------------------------
__global__ __launch_bounds__(TPB, 1) void nms_greedy_kernel(
    const float* __restrict__ bboxes, const float* __restrict__ scores,
    const float* __restrict__ nms_ptr, int N, int C,
    const u32* __restrict__ gidx, const u32* __restrict__ gK,
    u64* __restrict__ gkept)
{
    __shared__ __align__(16) char smem[63856];
    float4* boxesLds = (float4*)smem;
    u16*    keptR    = (u16*)(smem + 58368);
    u32*    ctl      = (u32*)(smem + 58976);
    float4* pubBox   = (float4*)(smem + 58992);

    const int tid = threadIdx.x;
    const int c   = blockIdx.x;
    const int cls = c + 1;
    const float nmsT = *nms_ptr;
    const int K = (int)gK[c];

    const u32* gidx_c = gidx + (size_t)c * MSORT;
    for (int r = tid; r < K; r += TPB)
        boxesLds[r] = ((const float4*)bboxes)[gidx_c[r]];
    if (tid == 0) { ctl[0] = 0; ctl[1] = 0; ctl[2] = 0; }
    __syncthreads();

    const int lane = tid & 63;
    const int wave = tid >> 6;

    // B = midpoint(T, nextafter(T)); cmp is >= iff nextafter(T) has even mantissa.
    const u32 tb = __float_as_uint(nmsT);
    const float Tn = __uint_as_float(tb + 1u);
    const double B = ((double)nmsT + (double)Tn) * 0.5;
    const bool geCmp = (((tb + 1u) & 1u) == 0u);

    const int smax = (K + 63) >> 6;            // <= 57
    int ret = geCmp ? greedy_nms<true >(boxesLds, keptR, pubBox, ctl, K, smax, B, lane, wave)
                    : greedy_nms<false>(boxesLds, keptR, pubBox, ctl, K, smax, B, lane, wave);

    if (ret >= 0) {                            // this wave set doneF: owns epilogue
        int kept = ret; if (kept > KPC) kept = KPC;
        u64* gkept_c = gkept + (size_t)c * KPC;
        for (int p = lane; p < kept; p += 64) {
            int rank = keptR[p];
            u32 idx  = gidx_c[rank];
            float sc = scores[(size_t)idx * C + cls];
            u32 flat = (u32)c * (u32)N + idx;  // top_k ties: lower flat first
            gkept_c[p] = ((u64)__float_as_uint(sc) << 32) | (u32)(~flat);
        }
        for (int p = kept + lane; p < KPC; p += 64) gkept_c[p] = 0;
    }
}

// ---------------------------------------------------------------------------
// Kernel 3: global top-Mout over nc*KPC kept keys: 2048-bin histogram select
// + 1024-slot LDS bitonic sort.
// ---------------------------------------------------------------------------
__global__ __launch_bounds__(1024) void nms_topk_kernel(
    const float* __restrict__ bboxes, const u64* __restrict__ gkept,
    int N, int nc, int Mout, float* __restrict__ out)
{
    __shared__ u32 hist[2048];
    __shared__ int chunk[64];
    __shared__ int selCount;
    __shared__ int bstarS;
    __shared__ u64 sel[SELCAP];

    const int tid = threadIdx.x;
    const int total = nc * KPC;

    for (int b = tid; b < 2048; b += 1024) hist[b] = 0;
    if (tid == 0) selCount = 0;
    __syncthreads();

    for (int t = tid; t < total; t += 1024) {
        u64 k = gkept[t];
        if (k) {
            int b = (int)((u32)(k >> 44)) - 0x3F000;
            b = b < 0 ? 0 : (b > 2047 ? 2047 : b);
            atomicAdd(&hist[b], 1u);
        }
    }
    __syncthreads();

    if (tid < 64) {
        int s = 0;
        #pragma unroll
        for (int b = 0; b < 32; b++) s += (int)hist[tid * 32 + b];
        chunk[tid] = s;
    }
    __syncthreads();

    if (tid == 0) {
        int acc = 0, ch = 63;
        for (; ch >= 0; ch--) {
            if (acc + chunk[ch] >= Mout) break;
            acc += chunk[ch];
        }
        int bs = 0;
        if (ch >= 0) {
            int b = (ch << 5) + 31;
            for (; b >= (ch << 5); b--) { acc += (int)hist[b]; if (acc >= Mout) break; }
            bs = (b < (ch << 5)) ? (ch << 5) : b;
        }
        bstarS = bs;
    }
    __syncthreads();
    const int bstar = bstarS;

    for (int t = tid; t < total; t += 1024) {
        u64 k = gkept[t];
        if (k) {
            int b = (int)((u32)(k >> 44)) - 0x3F000;
            b = b < 0 ? 0 : (b > 2047 ? 2047 : b);
            if (b >= bstar) {
                int p = atomicAdd(&selCount, 1);
                if (p < SELCAP) sel[p] = k;
            }
        }
    }
    __syncthreads();
    int cnt = selCount; if (cnt > SELCAP) cnt = SELCAP;
    for (int p = cnt + tid; p < SELCAP; p += 1024) sel[p] = 0;
    __syncthreads();

    for (int kk = 2; kk <= SELCAP; kk <<= 1) {
        for (int j = kk >> 1; j > 0; j >>= 1) {
            int i = tid;
            int ixj = i ^ j;
            if (i < SELCAP && ixj > i) {
                u64 a = sel[i], b = sel[ixj];
                if (((i & kk) == 0) ? (a < b) : (a > b)) { sel[i] = b; sel[ixj] = a; }
            }
            __syncthreads();
        }
    }

    for (int t = tid; t < Mout; t += 1024) {
        u64 k = (t < SELCAP) ? sel[t] : 0;
        float px1 = 0.f, py1 = 0.f, px2 = 0.f, py2 = 0.f, ps = 0.f, plab = -1.0f;
        if (k) {
            float s  = __uint_as_float((u32)(k >> 32));
            u32 flat = ~((u32)k);
            int cc   = (int)(flat / (u32)N);
            int box  = (int)(flat - (u32)cc * (u32)N);
            float4 bb = ((const float4*)bboxes)[box];
            px1 = bb.x; py1 = bb.y; px2 = bb.z; py2 = bb.w; ps = s;
            plab = (float)(cc + 1);
        }
        out[t * 5 + 0] = px1;
        out[t * 5 + 1] = py1;
        out[t * 5 + 2] = px2;
        out[t * 5 + 3] = py2;
        out[t * 5 + 4] = ps;
        out[Mout * 5 + t] = plab;
    }
}

extern "C" void kernel_launch(void* const* d_in, const int* in_sizes, int n_in,
                              void* d_out, int out_size, void* d_ws, size_t ws_size,
                              hipStream_t stream) {
    const float* bboxes = (const float*)d_in[0];
    const float* scores = (const float*)d_in[1];
    const float* conf   = (const float*)d_in[2];
    const float* nmsT   = (const float*)d_in[3];

    const int N    = in_sizes[0] / 4;        // 5000
    const int C    = in_sizes[1] / N;        // 81
    const int nc   = C - 1;                  // 80
    const int Mout = out_size / 6;           // 300

    // ws layout: [gidx: nc*MSORT u32 = 1.31 MB][gK: nc u32, padded][gkept: nc*KPC u64]
    char* wsb = (char*)d_ws;
    u32* gidx  = (u32*)wsb;
    u32* gK    = (u32*)(wsb + (size_t)nc * MSORT * sizeof(u32));
    u64* gkept = (u64*)(wsb + (size_t)nc * MSORT * sizeof(u32) + 1024);

    nms_sort_kernel<<<nc, TPB_S, 0, stream>>>(scores, conf, N, C, gidx, gK);
    nms_greedy_kernel<<<nc, TPB, 0, stream>>>(bboxes, scores, nmsT, N, C, gidx, gK, gkept);
    nms_topk_kernel<<<1, 1024, 0, stream>>>(bboxes, gkept, N, nc, Mout, (float*)d_out);
}

// Round 10
// 122.928 us; speedup vs baseline: 3.5096x; 2.7383x over previous
//
#include <hip/hip_runtime.h>

typedef unsigned long long u64;
typedef unsigned int u32;
typedef unsigned short u16;

#define MSORT 4096     // fallback sort capacity (power of 2)
#define TPB1  1024     // select kernel threads
#define TPBF  1024     // fallback kernel threads
#define BOXCAP 3648    // fallback: boxes staged in LDS (57 KB)
#define RSLOT_W 10     // fallback: register slots per wave
#define KPC   300      // kept recorded per class
#define SELCAP 1024
#define PREFR 64       // prefix-NMS rank budget (top-64 per class)

#define WG_SCOPE __HIP_MEMORY_SCOPE_WORKGROUP

__device__ __forceinline__ float boxArea(float4 b) {
    return __fmul_rn(__fsub_rn(b.z, b.x), __fsub_rn(b.w, b.y));
}

// exact numpy f32 semantics: RN32(inter/uni) > T  <=>  inter (cmp) B*uni in f64
template<bool GE>
__device__ __forceinline__ bool iou_gt(float4 a, float area_a, float4 b, float area_b, double B) {
    float ix1 = fmaxf(a.x, b.x), iy1 = fmaxf(a.y, b.y);
    float ix2 = fminf(a.z, b.z), iy2 = fminf(a.w, b.w);
    float iw  = fmaxf(__fsub_rn(ix2, ix1), 0.0f);
    float ih  = fmaxf(__fsub_rn(iy2, iy1), 0.0f);
    float inter = __fmul_rn(iw, ih);
    float uni   = __fsub_rn(__fadd_rn(area_a, area_b), inter);
    return GE ? ((double)inter >= B * (double)uni) : ((double)inter > B * (double)uni);
}

// monotone bin of a positive-float score's bit pattern (11 bits @ exp 126)
__device__ __forceinline__ int scoreBin(u32 bits) {
    int b = (int)(bits >> 12) - 0x3F000;
    return b < 0 ? 0 : (b > 2047 ? 2047 : b);
}

// ---------------------------------------------------------------------------
// wave-0 prefix greedy NMS over the top-R (R<=64) candidates, one per lane.
// Exact: greedy decisions for rank j depend only on kept ranks < j.
// Returns kept count; lane 0 writes output keys to gkept_c[0..nk).
// ---------------------------------------------------------------------------
template<bool GE>
__device__ __forceinline__ int prefix_nms_w0(
    const float* __restrict__ bboxes, const u64* __restrict__ keybuf,
    int R, double B, int tid, int c, int N, u64* __restrict__ gkept_c)
{
    u64 key = (tid < R) ? keybuf[tid] : 0;
    float4 bx = make_float4(0.f, 0.f, 0.f, 0.f);
    if (tid < R) bx = ((const float4*)bboxes)[(u32)key];
    float ar = boxArea(bx);
    u64 supB = (R >= 64) ? 0ull : (~0ull << R);
    int nk = 0;
    int i = -1;
    for (;;) {
        u64 mask = (i >= 63) ? 0ull : (~0ull << (i + 1));
        u64 alive = ~supB & mask;
        if (!alive) break;
        i = (int)__builtin_ctzll(alive);
        float4 bi;
        bi.x = __shfl(bx.x, i, 64); bi.y = __shfl(bx.y, i, 64);
        bi.z = __shfl(bx.z, i, 64); bi.w = __shfl(bx.w, i, 64);
        float ai = boxArea(bi);
        if (tid == 0) {
            u64 ki = keybuf[i];
            u32 flat = (u32)c * (u32)N + (u32)ki;   // top_k ties: lower flat first
            gkept_c[nk] = (ki & 0xFFFFFFFF00000000ull) | (u32)(~flat);
        }
        nk++;
        bool sup = (tid > i) && iou_gt<GE>(bi, ai, bx, ar, B);
        supB |= __ballot(sup);
    }
    return nk;
}

// ---------------------------------------------------------------------------
// Kernel 1: per class — histogram-select top-(PREFR+1) candidates (no full
// sort), sort those 256 slots, prefix-NMS top-64 -> exact kept' subset.
// Writes gkept (kept' + zero tail), gK (valid count), g65 (65th cand score
// bits or 0), gPre (tie/overflow pathology -> force fallback).
// ---------------------------------------------------------------------------
__global__ __launch_bounds__(TPB1, 1) void nms_select_kernel(
    const float* __restrict__ bboxes, const float* __restrict__ scores,
    const float* __restrict__ conf_ptr, const float* __restrict__ nms_ptr,
    int N, int C, u64* __restrict__ gkept,
    u32* __restrict__ gK, u32* __restrict__ g65, u32* __restrict__ gPre)
{
    __shared__ u32 hist[2048];
    __shared__ int chunk[64];
    __shared__ u64 keybuf[256];
    __shared__ int cntS, ncollS, bstarS, nkS;

    const int tid = threadIdx.x;
    const int c   = blockIdx.x;
    const int cls = c + 1;
    const float conf = *conf_ptr;
    const float nmsT = *nms_ptr;

    for (int b = tid; b < 2048; b += TPB1) hist[b] = 0;
    if (tid == 0) { cntS = 0; ncollS = 0; nkS = 0; }
    __syncthreads();

    for (int i = tid; i < N; i += TPB1) {
        float s = scores[(size_t)i * C + cls];
        if (s > conf) {
            atomicAdd(&cntS, 1);
            atomicAdd(&hist[scoreBin(__float_as_uint(s))], 1u);
        }
    }
    __syncthreads();
    const int K = cntS;
    const int target = K < (PREFR + 1) ? K : (PREFR + 1);

    if (tid < 64) {
        int s = 0;
        #pragma unroll
        for (int b = 0; b < 32; b++) s += (int)hist[tid * 32 + b];
        chunk[tid] = s;
    }
    __syncthreads();
    if (tid == 0) {
        int acc = 0, ch = 63;
        for (; ch >= 0; ch--) { if (acc + chunk[ch] >= target) break; acc += chunk[ch]; }
        int bs = 0;
        if (ch >= 0) {
            int b = (ch << 5) + 31;
            for (; b >= (ch << 5); b--) { acc += (int)hist[b]; if (acc >= target) break; }
            bs = (b < (ch << 5)) ? (ch << 5) : b;
        }
        bstarS = bs;
    }
    __syncthreads();
    const u32 tbits = (bstarS == 0) ? 0u : (((u32)bstarS + 0x3F000u) << 12);

    for (int i = tid; i < N; i += TPB1) {
        float s = scores[(size_t)i * C + cls];
        if (s > conf && __float_as_uint(s) >= tbits) {
            int p = atomicAdd(&ncollS, 1);
            if (p < 256) keybuf[p] = ((u64)__float_as_uint(s) << 32) | (u32)i;
        }
    }
    __syncthreads();
    const int ncoll = ncollS;
    const bool pre = (ncoll > 256);               // tie flood / low-score regime
    u64* gkept_c = gkept + (size_t)c * KPC;

    if (!pre) {
        for (int p = ncoll + tid; p < 256; p += TPB1) keybuf[p] = 0;
        __syncthreads();
        for (int kk = 2; kk <= 256; kk <<= 1) {   // sort 256 desc (key: score|idx)
            for (int j = kk >> 1; j > 0; j >>= 1) {
                for (int i = tid; i < 256; i += TPB1) {
                    int ixj = i ^ j;
                    if (ixj > i) {
                        u64 a = keybuf[i], b = keybuf[ixj];
                        if (((i & kk) == 0) ? (a < b) : (a > b)) { keybuf[i] = b; keybuf[ixj] = a; }
                    }
                }
                __syncthreads();
            }
        }
        const u32 tb = __float_as_uint(nmsT);
        const float Tn = __uint_as_float(tb + 1u);
        const double B = ((double)nmsT + (double)Tn) * 0.5;
        const bool geCmp = (((tb + 1u) & 1u) == 0u);
        if (tid < 64) {
            int R = ncoll < PREFR ? ncoll : PREFR;
            int nk = geCmp ? prefix_nms_w0<true >(bboxes, keybuf, R, B, tid, c, N, gkept_c)
                           : prefix_nms_w0<false>(bboxes, keybuf, R, B, tid, c, N, gkept_c);
            if (tid == 0) nkS = nk;
        }
        __syncthreads();
        const int nk = nkS;
        for (int p = nk + tid; p < KPC; p += TPB1) gkept_c[p] = 0;
    } else {
        for (int p = tid; p < KPC; p += TPB1) gkept_c[p] = 0;
    }
    if (tid == 0) {
        gK[c]   = (u32)K;
        g65[c]  = pre ? 0xFFFFFFFFu : ((ncoll >= PREFR + 1) ? (u32)(keybuf[PREFR] >> 32) : 0u);
        gPre[c] = pre ? 1u : 0u;
    }
}

// ---------------------------------------------------------------------------
// Kernel 2: pool kept' -> theta lower bound (bin edge of Mout-th largest),
// per-class needFull flags. gCtl[0]=thetaBits, gCtl[1+c]=needFull.
// ---------------------------------------------------------------------------
__global__ __launch_bounds__(1024) void nms_theta_kernel(
    const u64* __restrict__ gkept, const u32* __restrict__ gK,
    const u32* __restrict__ g65, const u32* __restrict__ gPre,
    int nc, int Mout, u32* __restrict__ gCtl)
{
    __shared__ u32 hist[2048];
    __shared__ int chunk[64];
    __shared__ u32 thetaS;
    const int tid = threadIdx.x;
    const int total = nc * KPC;
    for (int b = tid; b < 2048; b += 1024) hist[b] = 0;
    __syncthreads();
    for (int t = tid; t < total; t += 1024) {
        u64 k = gkept[t];
        if (k) atomicAdd(&hist[scoreBin((u32)(k >> 32))], 1u);
    }
    __syncthreads();
    if (tid < 64) {
        int s = 0;
        #pragma unroll
        for (int b = 0; b < 32; b++) s += (int)hist[tid * 32 + b];
        chunk[tid] = s;
    }
    __syncthreads();
    if (tid == 0) {
        int tot = 0;
        for (int ch = 0; ch < 64; ch++) tot += chunk[ch];
        u32 theta = 0u;
        if (tot >= Mout) {
            int acc = 0, ch = 63;
            for (; ch >= 0; ch--) { if (acc + chunk[ch] >= Mout) break; acc += chunk[ch]; }
            int b = (ch << 5) + 31;
            for (; b >= (ch << 5); b--) { acc += (int)hist[b]; if (acc >= Mout) break; }
            int bs = (b < (ch << 5)) ? (ch << 5) : b;
            theta = (bs <= 0) ? 0u : (((u32)bs + 0x3F000u) << 12);
        }
        gCtl[0] = theta;
        thetaS  = theta;
    }
    __syncthreads();
    const u32 theta = thetaS;
    for (int c2 = tid; c2 < nc; c2 += 1024) {
        u32 need = gPre[c2];
        if (gK[c2] > PREFR && g65[c2] >= theta) need = 1u;   // theta==0 -> always
        gCtl[1 + c2] = need;
    }
}

// ---------------------------------------------------------------------------
// Fallback greedy (R8-lazy producer/consumer, 4 waves) with stop at theta.
// Returns kept count if this wave set doneF (owns epilogue), else -1.
// ---------------------------------------------------------------------------
template<bool GE>
__device__ __forceinline__ u64 sweep_own(
    float4 bi, float area_i, const float4 (&breg)[RSLOT_W],
    const float (&areaj)[RSLOT_W], const float4* __restrict__ boxesLds,
    int base, int nslots, int lane, double B)
{
    u64 ns = 0;
    #pragma unroll
    for (int t = 0; t < RSLOT_W; t++)
        ns |= ((u64)iou_gt<GE>(bi, area_i, breg[t], areaj[t], B)) << (base + t);
    for (int t = RSLOT_W; t < nslots; t++) {
        float4 bj = boxesLds[((base + t) << 6) | lane];
        ns |= ((u64)iou_gt<GE>(bi, area_i, bj, boxArea(bj), B)) << (base + t);
    }
    return ns;
}

template<bool GE>
__device__ __forceinline__ int greedy_full(
    const float4* __restrict__ boxesLds, u16* __restrict__ keptR,
    float4* __restrict__ pubBox, u32* __restrict__ ctl,
    const u32* __restrict__ gsi_c, const float* __restrict__ scores,
    int cls, int C, u32 thetaBits,
    int K, int smax, double B, int lane, int wave)
{
    const int SW   = (smax + 3) >> 2;
    const int base = (wave * SW < smax) ? wave * SW : smax;
    const int end  = (base + SW < smax) ? base + SW : smax;
    const int nslots = end - base;

    float4 breg[RSLOT_W];
    float  areaj[RSLOT_W];
    #pragma unroll
    for (int t = 0; t < RSLOT_W; t++) {
        float4 b = boxesLds[((base + t) << 6) | lane];
        breg[t] = b;
        areaj[t] = boxArea(b);
    }

    u64 sup;
    {
        int t = (lane < K) ? ((K - lane + 63) >> 6) : 0;
        sup = (t >= 64) ? 0ull : (~0ull << t);
    }

    u32 seen = 0;
    if (wave != 0) {
        for (;;) {
            u32 d  = __hip_atomic_load(&ctl[2], __ATOMIC_ACQUIRE, WG_SCOPE);
            u32 cn = __hip_atomic_load(&ctl[0], __ATOMIC_ACQUIRE, WG_SCOPE);
            bool prog = (seen < cn);
            while (seen < cn) {
                float4 bi = pubBox[seen]; seen++;
                sup |= sweep_own<GE>(bi, boxArea(bi), breg, areaj, boxesLds, base, nslots, lane, B);
            }
            if (d) return -1;
            u32 aw = __hip_atomic_load(&ctl[1], __ATOMIC_ACQUIRE, WG_SCOPE);
            if (aw == (u32)wave) {
                u32 cn2 = __hip_atomic_load(&ctl[0], __ATOMIC_ACQUIRE, WG_SCOPE);
                while (seen < cn2) {
                    float4 bi = pubBox[seen]; seen++;
                    sup |= sweep_own<GE>(bi, boxArea(bi), breg, areaj, boxesLds, base, nslots, lane, B);
                }
                break;
            }
            if (!prog) __builtin_amdgcn_s_sleep(1);
        }
    }

    u32 nk = seen;
    const u32 seen0 = seen;
    int scur = base - 1;
    float4 bcur = make_float4(0.f, 0.f, 0.f, 0.f);
    float  acur = 0.f;
    int js = base << 6;

    for (;;) {
        int s = js >> 6;
        while (s > scur) {
            scur++;
            if (scur < end) {
                bcur = boxesLds[(scur << 6) | lane];
                acur = boxArea(bcur);
                u64 bit = 0;
                for (u32 k = seen0; k < nk; k++) {
                    float4 bk = pubBox[k];
                    bit |= ((u64)iou_gt<GE>(bk, boxArea(bk), bcur, acur, B));
                }
                sup |= bit << scur;
            }
        }
        if (scur >= end) {
            if (wave == 3) {
                if (lane == 0) __hip_atomic_store(&ctl[2], 1u, __ATOMIC_RELEASE, WG_SCOPE);
                return (int)nk;
            }
            if (lane == 0) __hip_atomic_store(&ctl[1], (u32)(wave + 1), __ATOMIC_RELEASE, WG_SCOPE);
            return -1;
        }
        u64 bal = __ballot((int)(((~sup) >> scur) & 1ull)) & (~0ull << (js & 63));
        if (bal == 0) { js = (scur + 1) << 6; continue; }
        int i = (scur << 6) + (int)__builtin_ctzll(bal);

        if (thetaBits) {                                   // stop: below theta can't matter
            u32 idx = gsi_c[i];
            float sc = scores[(size_t)idx * C + cls];
            if (__float_as_uint(sc) < thetaBits) {
                if (lane == 0) __hip_atomic_store(&ctl[2], 1u, __ATOMIC_RELEASE, WG_SCOPE);
                return (int)nk;
            }
        }
        float4 bi = boxesLds[i];
        if (lane == 0) { pubBox[nk] = bi; keptR[nk] = (u16)i; }
        nk++;
        if (nk >= KPC) {
            if (lane == 0) {
                __hip_atomic_store(&ctl[0], nk, __ATOMIC_RELEASE, WG_SCOPE);
                __hip_atomic_store(&ctl[2], 1u, __ATOMIC_RELEASE, WG_SCOPE);
            }
            return (int)nk;
        }
        if (lane == 0) __hip_atomic_store(&ctl[0], nk, __ATOMIC_RELEASE, WG_SCOPE);
        sup |= ((u64)iou_gt<GE>(bi, boxArea(bi), bcur, acur, B)) << scur;
        js = i + 1;
    }
}

// ---------------------------------------------------------------------------
// Kernel 3: full per-class NMS for flagged classes only (sort @1024 thr,
// greedy on waves 0-3). Fast classes return immediately.
// ---------------------------------------------------------------------------
__global__ __launch_bounds__(TPBF, 1) void nms_full_kernel(
    const float* __restrict__ bboxes, const float* __restrict__ scores,
    const float* __restrict__ conf_ptr, const float* __restrict__ nms_ptr,
    int N, int C, const u32* __restrict__ gCtl,
    u32* __restrict__ gsi, u64* __restrict__ gkept)
{
    const int c = blockIdx.x;
    if (gCtl[1 + c] == 0u) return;

    __shared__ __align__(16) char smem[63856];
    u64*    sortbuf  = (u64*)smem;             // [0,32768)
    float4* boxesLds = (float4*)smem;          // [0,58368)
    u16*    keptR    = (u16*)(smem + 58368);
    u32*    ctl      = (u32*)(smem + 58976);
    float4* pubBox   = (float4*)(smem + 58992);
    __shared__ int cntS;

    const int tid = threadIdx.x;
    const int cls = c + 1;
    const float conf = *conf_ptr;
    const float nmsT = *nms_ptr;
    const u32 thetaBits = gCtl[0];

    if (tid == 0) cntS = 0;
    __syncthreads();
    for (int i = tid; i < N; i += TPBF) {
        float s = scores[(size_t)i * C + cls];
        if (s > conf) {
            int p = atomicAdd(&cntS, 1);
            if (p < MSORT) sortbuf[p] = ((u64)__float_as_uint(s) << 32) | (u32)i;
        }
    }
    __syncthreads();
    int K = cntS; if (K > BOXCAP) K = BOXCAP;
    int M = 64; while (M < K) M <<= 1;
    for (int p = K + tid; p < M; p += TPBF) sortbuf[p] = 0;
    __syncthreads();
    for (int kk = 2; kk <= M; kk <<= 1) {
        for (int j = kk >> 1; j > 0; j >>= 1) {
            for (int i = tid; i < M; i += TPBF) {
                int ixj = i ^ j;
                if (ixj > i) {
                    u64 a = sortbuf[i], b = sortbuf[ixj];
                    if (((i & kk) == 0) ? (a < b) : (a > b)) { sortbuf[i] = b; sortbuf[ixj] = a; }
                }
            }
            __syncthreads();
        }
    }
    u32 myIdx[MSORT / TPBF];
    #pragma unroll
    for (int t = 0; t < MSORT / TPBF; t++) myIdx[t] = (u32)sortbuf[t * TPBF + tid];
    __syncthreads();
    u32* gsi_c = gsi + (size_t)c * BOXCAP;
    #pragma unroll
    for (int t = 0; t < MSORT / TPBF; t++) {
        int r = t * TPBF + tid;
        if (r < K) {
            u32 idx = myIdx[t];
            gsi_c[r] = idx;
            boxesLds[r] = ((const float4*)bboxes)[idx];
        }
    }
    if (tid == 0) { ctl[0] = 0; ctl[1] = 0; ctl[2] = 0; }
    __syncthreads();
    if (tid >= 256) return;

    const int lane = tid & 63;
    const int wave = tid >> 6;
    const u32 tb = __float_as_uint(nmsT);
    const float Tn = __uint_as_float(tb + 1u);
    const double B = ((double)nmsT + (double)Tn) * 0.5;
    const bool geCmp = (((tb + 1u) & 1u) == 0u);
    const int smax = (K + 63) >> 6;

    int ret = geCmp ? greedy_full<true >(boxesLds, keptR, pubBox, ctl, gsi_c, scores, cls, C, thetaBits, K, smax, B, lane, wave)
                    : greedy_full<false>(boxesLds, keptR, pubBox, ctl, gsi_c, scores, cls, C, thetaBits, K, smax, B, lane, wave);
    if (ret >= 0) {
        int kept = ret; if (kept > KPC) kept = KPC;
        u64* gkept_c = gkept + (size_t)c * KPC;
        for (int p = lane; p < kept; p += 64) {
            int rank = keptR[p];
            u32 idx = gsi_c[rank];
            float sc = scores[(size_t)idx * C + cls];
            u32 flat = (u32)c * (u32)N + idx;
            gkept_c[p] = ((u64)__float_as_uint(sc) << 32) | (u32)(~flat);
        }
        for (int p = kept + lane; p < KPC; p += 64) gkept_c[p] = 0;
    }
}

// ---------------------------------------------------------------------------
// Kernel 4: global top-Mout over nc*KPC kept keys.
// ---------------------------------------------------------------------------
__global__ __launch_bounds__(1024) void nms_topk_kernel(
    const float* __restrict__ bboxes, const u64* __restrict__ gkept,
    int N, int nc, int Mout, float* __restrict__ out)
{
    __shared__ u32 hist[2048];
    __shared__ int chunk[64];
    __shared__ int selCount;
    __shared__ int bstarS;
    __shared__ u64 sel[SELCAP];

    const int tid = threadIdx.x;
    const int total = nc * KPC;

    for (int b = tid; b < 2048; b += 1024) hist[b] = 0;
    if (tid == 0) selCount = 0;
    __syncthreads();

    for (int t = tid; t < total; t += 1024) {
        u64 k = gkept[t];
        if (k) atomicAdd(&hist[scoreBin((u32)(k >> 32))], 1u);
    }
    __syncthreads();

    if (tid < 64) {
        int s = 0;
        #pragma unroll
        for (int b = 0; b < 32; b++) s += (int)hist[tid * 32 + b];
        chunk[tid] = s;
    }
    __syncthreads();

    if (tid == 0) {
        int acc = 0, ch = 63;
        for (; ch >= 0; ch--) {
            if (acc + chunk[ch] >= Mout) break;
            acc += chunk[ch];
        }
        int bs = 0;
        if (ch >= 0) {
            int b = (ch << 5) + 31;
            for (; b >= (ch << 5); b--) { acc += (int)hist[b]; if (acc >= Mout) break; }
            bs = (b < (ch << 5)) ? (ch << 5) : b;
        }
        bstarS = bs;
    }
    __syncthreads();
    const int bstar = bstarS;

    for (int t = tid; t < total; t += 1024) {
        u64 k = gkept[t];
        if (k) {
            int b = scoreBin((u32)(k >> 32));
            if (b >= bstar) {
                int p = atomicAdd(&selCount, 1);
                if (p < SELCAP) sel[p] = k;
            }
        }
    }
    __syncthreads();
    int cnt = selCount; if (cnt > SELCAP) cnt = SELCAP;
    for (int p = cnt + tid; p < SELCAP; p += 1024) sel[p] = 0;
    __syncthreads();

    for (int kk = 2; kk <= SELCAP; kk <<= 1) {
        for (int j = kk >> 1; j > 0; j >>= 1) {
            int i = tid;
            int ixj = i ^ j;
            if (i < SELCAP && ixj > i) {
                u64 a = sel[i], b = sel[ixj];
                if (((i & kk) == 0) ? (a < b) : (a > b)) { sel[i] = b; sel[ixj] = a; }
            }
            __syncthreads();
        }
    }

    for (int t = tid; t < Mout; t += 1024) {
        u64 k = (t < SELCAP) ? sel[t] : 0;
        float px1 = 0.f, py1 = 0.f, px2 = 0.f, py2 = 0.f, ps = 0.f, plab = -1.0f;
        if (k) {
            float s  = __uint_as_float((u32)(k >> 32));
            u32 flat = ~((u32)k);
            int cc   = (int)(flat / (u32)N);
            int box  = (int)(flat - (u32)cc * (u32)N);
            float4 bb = ((const float4*)bboxes)[box];
            px1 = bb.x; py1 = bb.y; px2 = bb.z; py2 = bb.w; ps = s;
            plab = (float)(cc + 1);
        }
        out[t * 5 + 0] = px1;
        out[t * 5 + 1] = py1;
        out[t * 5 + 2] = px2;
        out[t * 5 + 3] = py2;
        out[t * 5 + 4] = ps;
        out[Mout * 5 + t] = plab;
    }
}

extern "C" void kernel_launch(void* const* d_in, const int* in_sizes, int n_in,
                              void* d_out, int out_size, void* d_ws, size_t ws_size,
                              hipStream_t stream) {
    const float* bboxes = (const float*)d_in[0];
    const float* scores = (const float*)d_in[1];
    const float* conf   = (const float*)d_in[2];
    const float* nmsT   = (const float*)d_in[3];

    const int N    = in_sizes[0] / 4;        // 5000
    const int C    = in_sizes[1] / N;        // 81
    const int nc   = C - 1;                  // 80
    const int Mout = out_size / 6;           // 300

    // ws layout: [gsi: nc*BOXCAP u32][gkept: nc*KPC u64][gK|g65|gPre|gCtl u32]
    char* wsb = (char*)d_ws;
    size_t off = 0;
    u32* gsi   = (u32*)(wsb + off); off += (size_t)nc * BOXCAP * sizeof(u32);
    u64* gkept = (u64*)(wsb + off); off += (size_t)nc * KPC * sizeof(u64);
    u32* gK    = (u32*)(wsb + off); off += (size_t)((nc + 2) & ~1) * sizeof(u32);
    u32* g65   = (u32*)(wsb + off); off += (size_t)((nc + 2) & ~1) * sizeof(u32);
    u32* gPre  = (u32*)(wsb + off); off += (size_t)((nc + 2) & ~1) * sizeof(u32);
    u32* gCtl  = (u32*)(wsb + off);

    nms_select_kernel<<<nc, TPB1, 0, stream>>>(bboxes, scores, conf, nmsT, N, C, gkept, gK, g65, gPre);
    nms_theta_kernel<<<1, 1024, 0, stream>>>(gkept, gK, g65, gPre, nc, Mout, gCtl);
    nms_full_kernel<<<nc, TPBF, 0, stream>>>(bboxes, scores, conf, nmsT, N, C, gCtl, gsi, gkept);
    nms_topk_kernel<<<1, 1024, 0, stream>>>(bboxes, gkept, N, nc, Mout, (float*)d_out);
}